// Round 3
// baseline (97.061 us; speedup 1.0000x reference)
//
#include <hip/hip_runtime.h>
#include <math.h>

// S4D kernel materialization:
//   dt = exp(inv_dt[h]);  A = -exp(A_real) + i*A_imag;  dtA = dt*A
//   Cm = (B*C) * (exp(dtA)-1)/A          (complex, per h,n)
//   K[h,l] = 2 * Re( sum_n Cm[h,n] * exp(dtA[h,n] * l) )
//
// H=1024, N=64, CH=1, L=2048. Output (1,H,L) float32 = 8 MB.
//
// R9: recover occupancy + kill in-loop gate latency. R8 (floor model:
// total 78.9 = ~61.5 harness fills + ~17.4 kernel) was SLOWER than
// ungated R6 (~13.9) despite cutting ~60% of j-steps:
//   a) __launch_bounds__(TPB,2) halved residency to 2 blocks/CU ->
//      prologue/barrier/epilogue latency no longer hidden by
//      cross-block overlap (1024 blocks = 4 rounds/CU).
//   b) gbs[] LDS read + readfirstlane INSIDE the g-loop: ~120cy
//      serialized stall per pack.
// Fixes: __launch_bounds__(TPB,4) (peak live ~110 VGPR fits 128; R7's
// spill was the vector if-conversion, gone since R8's scalar guards);
// hoist all 4 pack bounds via one int4 LDS read + 4 readfirstlane into
// SGPRs before a fully-unrolled g-loop (gates become pure s_cbranch).
//
// R7/R8: decay truncation. Re(dtA)<0, chain decays e^{-lam} per step,
// lam = -64*dre (median ~1.2): per-n bound jb = O(8/lam) is
// wave-uniform. Chains rank-sorted by jb, packs of 4 homogeneous,
// sorted groups dealt round-robin across waves. Guards are scalar
// (SGPR) -> no exec-mask if-conversion. Truncation error < 64*eps.
//
// Structure = R6: one h per block, 4 waves x 16 n, lane owns
// l = lane + 64*j (j=0..31), 2nd-order real recurrence
// x_{j+1} = 2Re(W) x_j - |W|^2 x_{j-1}, W = exp(dtA*64), packed fp32
// (VOP3P) over chain pairs.

#define HH 1024
#define NN 64
#define TPB 256
#define NWAVE 4
#define NPW 16         // n per wave
#define STEP 64        // lanes per wave = l-stride per recurrence step
#define LPT 32         // 2048 / 64
#define RJ 33          // padded j-stride in reduce buffer
#define LOG2E  1.4426950408889634f
#define INV2PI 0.15915494309189535f
#define TRUNC_EPS 1e-5f

typedef float v2f __attribute__((ext_vector_type(2)));

// one unrolled span of the packed 2nd-order recurrence; J0/J1 literal
#define STEP8(J0, J1)                                              \
    _Pragma("unroll")                                              \
    for (int j = (J0); j < (J1); ++j) {                            \
        acc2[j] += xc0;                                            \
        acc2[j] += xc1;                                            \
        v2f t0 = nb0 * xp0;                                        \
        v2f t1 = nb1 * xp1;                                        \
        v2f n0v = __builtin_elementwise_fma(aa0, xc0, t0);         \
        v2f n1v = __builtin_elementwise_fma(aa1, xc1, t1);         \
        xp0 = xc0; xc0 = n0v;                                      \
        xp1 = xc1; xc1 = n1v;                                      \
    }

__global__ __launch_bounds__(TPB, 4) void s4d_pk_kernel(
    const float* __restrict__ A_real,
    const float* __restrict__ A_imag,
    const float* __restrict__ B,
    const float* __restrict__ C,
    const float* __restrict__ inv_dt,
    float* __restrict__ out,
    int L)
{
    __shared__ float4 pA[NN];              // (dre*log2e, dim/2pi, 2*Cm.re, 2*Cm.im)
    __shared__ float4 pW[NN];              // (Wr, Wi, 2*Wr, -|W|^2)
    __shared__ int    jb_sh[NN];           // per-n truncation bound
    __shared__ int    gbs[NN / 4];         // per-group-of-4 bound (max)
    __shared__ float  red[NWAVE * STEP * RJ];  // partials, ~33.8 KB

    const int h    = blockIdx.x;
    const int t    = threadIdx.x;
    const int lane = t & 63;
    const int w    = t >> 6;

    float4 myA, myW;
    int myjb = 0;

    if (t < NN) {
        const int n  = t;
        const int hn = h * NN + n;
        float Ar = A_real[hn];
        float Ai = A_imag[hn];
        float dt = expf(inv_dt[h]);          // rate = 1.0
        float are = -expf(Ar);               // Re(A) = -exp(A_real)
        float dre = dt * are;                // Re(dtA)  (< 0)
        float dim = dt * Ai;                 // Im(dtA)
        // exp(dtA) - 1
        float er = expf(dre);
        float s, c;
        sincosf(dim, &s, &c);
        float em1r = er * c - 1.0f;
        float em1i = er * s;
        // (exp(dtA)-1)/A  via conj(A)/|A|^2
        float inv = 1.0f / (are * are + Ai * Ai);
        float zr = (em1r * are + em1i * Ai) * inv;
        float zi = (em1i * are - em1r * Ai) * inv;
        // Bc * Cc
        float br = B[2 * hn],  bi = B[2 * hn + 1];
        float Cr = C[2 * hn],  Ci = C[2 * hn + 1];
        float bcr = br * Cr - bi * Ci;
        float bci = br * Ci + bi * Cr;
        // Cm = (Bc*Cc) * z, fold in the final 2x
        float cmr = bcr * zr - bci * zi;
        float cmi = bcr * zi + bci * zr;

        float dreL = dre * LOG2E;
        float dimR = dim * INV2PI;
        // W = exp(dtA * STEP)
        float we = exp2f(dreL * (float)STEP);   // e^{dre*64} = e^{-lam}
        float wx = dimR * (float)STEP;
        float wf = wx - floorf(wx);
        float Wc = __builtin_amdgcn_cosf(wf);
        float Ws = __builtin_amdgcn_sinf(wf);
        float Wr = we * Wc, Wi = we * Ws;
        myA = make_float4(dreL, dimR, 2.0f * cmr, 2.0f * cmi);
        myW = make_float4(Wr, Wi, 2.0f * Wr, -(Wr * Wr + Wi * Wi));

        // truncation bound: |2Cm| e^{-lam*jb} / (1 - e^{-lam}) < eps
        float amp = 2.0f * sqrtf(cmr * cmr + cmi * cmi);
        float lam = -(dre * (float)STEP);       // > 0
        float om  = 1.0f - we;                  // 1 - e^{-lam}
        float v   = logf(amp / (TRUNC_EPS * om)) / lam;
        myjb = 32;                              // NaN/inf-safe default
        if (v < 31.0f) myjb = (v > 1.0f) ? (int)ceilf(v) : 1;
        jb_sh[n] = myjb;
    }
    __syncthreads();

    if (t < NN) {
        // O(N^2) rank sort by jb (ascending, index tie-break -> bijective)
        int rank = 0;
        for (int m = 0; m < NN; ++m) {
            int jm = jb_sh[m];
            rank += (jm < myjb || (jm == myjb && m < t)) ? 1 : 0;
        }
        // sorted group G = rank>>2 dealt round-robin: wave = G&3,
        // position within wave = G>>2. k = rank&3 within the pack.
        int G = rank >> 2, k = rank & 3;
        int slot = (G & 3) * NPW + (G >> 2) * 4 + k;
        pA[slot] = myA;
        pW[slot] = myW;
        if (k == 3) gbs[(G & 3) * 4 + (G >> 2)] = myjb;  // max of the pack
    }
    __syncthreads();

    v2f acc2[LPT];
#pragma unroll
    for (int j = 0; j < LPT; ++j) acc2[j] = (v2f){0.0f, 0.0f};

    const float tf = (float)lane;
    const int n0 = w * NPW;

    // hoist all 4 pack bounds to SGPRs once: one int4 LDS read (16B
    // aligned), 4 readfirstlane. Gates below are pure s_cmp/s_cbranch
    // with zero in-loop memory latency.
    const int4 gbv = *reinterpret_cast<const int4*>(&gbs[w * 4]);
    const int gb0 = __builtin_amdgcn_readfirstlane(gbv.x);
    const int gb1 = __builtin_amdgcn_readfirstlane(gbv.y);
    const int gb2 = __builtin_amdgcn_readfirstlane(gbv.z);
    const int gb3 = __builtin_amdgcn_readfirstlane(gbv.w);

#pragma unroll
    for (int g = 0; g < NPW; g += 4) {
        const int gb = (g == 0) ? gb0 : (g == 4) ? gb1 : (g == 8) ? gb2 : gb3;

        // scalar startup for 4 chains (3 trans each), then pack into 2 pairs
        float x0s[4], x1s[4], aas[4], nbs[4];
#pragma unroll
        for (int k = 0; k < 4; ++k) {
            const float4 p  = pA[n0 + g + k];   // wave-uniform -> LDS broadcast
            const float4 ww = pW[n0 + g + k];
            // z0 = 2*Cm * exp(dtA * lane)
            float e = __builtin_amdgcn_exp2f(p.x * tf);
            float f = __builtin_amdgcn_fractf(p.y * tf);
            float c = __builtin_amdgcn_cosf(f);
            float s = __builtin_amdgcn_sinf(f);
            float er = e * c, ei = e * s;
            float sr = p.z * er - p.w * ei;     // x0 = Re(z0)
            float si = p.z * ei + p.w * er;
            x0s[k] = sr;
            x1s[k] = sr * ww.x - si * ww.y;     // x1 = Re(z0 * W)
            aas[k] = ww.z;                      // 2*Re(W)
            nbs[k] = ww.w;                      // -|W|^2
        }
        v2f xp0 = (v2f){x0s[0], x0s[1]}, xc0 = (v2f){x1s[0], x1s[1]};
        v2f xp1 = (v2f){x0s[2], x0s[3]}, xc1 = (v2f){x1s[2], x1s[3]};
        const v2f aa0 = (v2f){aas[0], aas[1]}, nb0 = (v2f){nbs[0], nbs[1]};
        const v2f aa1 = (v2f){aas[2], aas[3]}, nb1 = (v2f){nbs[2], nbs[3]};

        acc2[0] += xp0 + xp1;                   // j = 0 contribution

        // block 0 (j=1..7) always runs; later 8-blocks gated by the
        // pack bound (terms j>=gb are < eps in magnitude)
        STEP8(1, 8)
        if (gb > 8)  { STEP8(8, 16)  }
        if (gb > 16) { STEP8(16, 24) }
        if (gb > 24) { STEP8(24, 32) }
    }

    // stash this wave's 32 partials (horizontal add of the chain pair here);
    // lane stride RJ=33 floats keeps bank aliasing <=2-way (free)
    {
        float* dst = &red[(w * STEP + lane) * RJ];
#pragma unroll
        for (int j = 0; j < LPT; ++j) dst[j] = acc2[j].x + acc2[j].y;
    }
    __syncthreads();

    // sum the 4 wave-partials; 8 outputs per thread, coalesced stores
#pragma unroll
    for (int q = 0; q < 8; ++q) {
        int p  = t + TPB * q;          // 0..2047
        int j  = p >> 6;
        int l2 = p & 63;
        float sum = 0.0f;
#pragma unroll
        for (int v = 0; v < NWAVE; ++v)
            sum += red[(v * STEP + l2) * RJ + j];
        out[h * L + p] = sum;
    }
}

extern "C" void kernel_launch(void* const* d_in, const int* in_sizes, int n_in,
                              void* d_out, int out_size, void* d_ws, size_t ws_size,
                              hipStream_t stream) {
    const float* A_real = (const float*)d_in[0];
    const float* A_imag = (const float*)d_in[1];
    const float* B      = (const float*)d_in[2];
    const float* C      = (const float*)d_in[3];
    const float* inv_dt = (const float*)d_in[4];
    int L = out_size / HH;   // 2048

    s4d_pk_kernel<<<HH, TPB, 0, stream>>>(A_real, A_imag, B, C, inv_dt,
                                          (float*)d_out, L);
}

// Round 4
// 74.898 us; speedup vs baseline: 1.2959x; 1.2959x over previous
//
#include <hip/hip_runtime.h>
#include <math.h>

// S4D kernel materialization:
//   dt = exp(inv_dt[h]);  A = -exp(A_real) + i*A_imag;  dtA = dt*A
//   Cm = (B*C) * (exp(dtA)-1)/A          (complex, per h,n)
//   K[h,l] = 2 * Re( sum_n Cm[h,n] * exp(dtA[h,n] * l) )
//
// H=1024, N=64, CH=1, L=2048. Output (1,H,L) float32 = 8 MB.
//
// R10: revert to R6 (proven 75.6 us total / ~13.9 us kernel). The decay-
// truncation family (R7-R9) was mathematically correct (absmax
// bit-identical) but structurally unprofitable:
//   R7: vector-conditional gates + 128-VGPR cap -> acc2 spill to
//       scratch (VGPR_Count=64, 150MB scratch traffic, 57 us).
//   R8: scalar gates + 256-VGPR cap -> no spill, but 2 blocks/CU;
//       prologue/barrier/epilogue latency exposed (17.4 us).
//   R9: scalar gates + 128 cap + full g-unroll -> spill again (~28-35us;
//       run also showed harness fills 12% slower = +-5-7us total noise).
// Conclusion: straight-line inner loop fits 128 VGPRs at 4 blocks/CU;
// ANY gated variant either spills (cap 128) or loses residency (cap
// 256). Theoretical truncation prize (~7us) < harness noise. Total is
// dominated by ~61us of harness poison-fills at HBM ceiling.
//
// R6: packed fp32. R5 measurement: kernel ~13.9 us/rep, VALUBusy 81%,
// effective clock ~1.5 GHz under dense fp32 (m07: 103 TF full-chip = 65% of
// 2.4GHz spec). VALU-issue bound -> cut instructions with VOP3P packed fp32:
// pair the n recurrence chains into float2 registers; inner step =
// v_pk_mul + v_pk_fma + v_pk_add per TWO elements (1.5 instr/elem vs 3).
// Structure otherwise = R4: one h per block, 4 waves x 16 n, lane owns
// l = lane + 64*j (j=0..31), 2nd-order real recurrence
// x_{j+1} = 2Re(W) x_j - |W|^2 x_{j-1}, W = exp(dtA*64).

#define HH 1024
#define NN 64
#define TPB 256
#define NWAVE 4
#define NPW 16         // n per wave
#define STEP 64        // lanes per wave = l-stride per recurrence step
#define LPT 32         // 2048 / 64
#define RJ 33          // padded j-stride in reduce buffer
#define LOG2E  1.4426950408889634f
#define INV2PI 0.15915494309189535f

typedef float v2f __attribute__((ext_vector_type(2)));

__global__ __launch_bounds__(TPB, 4) void s4d_pk_kernel(
    const float* __restrict__ A_real,
    const float* __restrict__ A_imag,
    const float* __restrict__ B,
    const float* __restrict__ C,
    const float* __restrict__ inv_dt,
    float* __restrict__ out,
    int L)
{
    __shared__ float4 pA[NN];              // (dre*log2e, dim/2pi, 2*Cm.re, 2*Cm.im)
    __shared__ float4 pW[NN];              // (Wr, Wi, 2*Wr, -|W|^2)
    __shared__ float red[NWAVE * STEP * RJ];  // partials, ~33.8 KB

    const int h    = blockIdx.x;
    const int t    = threadIdx.x;
    const int lane = t & 63;
    const int w    = t >> 6;

    if (t < NN) {
        const int n  = t;
        const int hn = h * NN + n;
        float Ar = A_real[hn];
        float Ai = A_imag[hn];
        float dt = expf(inv_dt[h]);          // rate = 1.0
        float are = -expf(Ar);               // Re(A) = -exp(A_real)
        float dre = dt * are;                // Re(dtA)  (<= 0)
        float dim = dt * Ai;                 // Im(dtA)
        // exp(dtA) - 1
        float er = expf(dre);
        float s, c;
        sincosf(dim, &s, &c);
        float em1r = er * c - 1.0f;
        float em1i = er * s;
        // (exp(dtA)-1)/A  via conj(A)/|A|^2
        float inv = 1.0f / (are * are + Ai * Ai);
        float zr = (em1r * are + em1i * Ai) * inv;
        float zi = (em1i * are - em1r * Ai) * inv;
        // Bc * Cc
        float br = B[2 * hn],  bi = B[2 * hn + 1];
        float Cr = C[2 * hn],  Ci = C[2 * hn + 1];
        float bcr = br * Cr - bi * Ci;
        float bci = br * Ci + bi * Cr;
        // Cm = (Bc*Cc) * z, fold in the final 2x
        float cmr = bcr * zr - bci * zi;
        float cmi = bcr * zi + bci * zr;

        float dreL = dre * LOG2E;
        float dimR = dim * INV2PI;
        // W = exp(dtA * STEP)
        float we = exp2f(dreL * (float)STEP);
        float wx = dimR * (float)STEP;
        float wf = wx - floorf(wx);
        float Wc = __builtin_amdgcn_cosf(wf);
        float Ws = __builtin_amdgcn_sinf(wf);
        float Wr = we * Wc, Wi = we * Ws;
        pA[n] = make_float4(dreL, dimR, 2.0f * cmr, 2.0f * cmi);
        pW[n] = make_float4(Wr, Wi, 2.0f * Wr, -(Wr * Wr + Wi * Wi));
    }
    __syncthreads();

    v2f acc2[LPT];
#pragma unroll
    for (int j = 0; j < LPT; ++j) acc2[j] = (v2f){0.0f, 0.0f};

    const float tf = (float)lane;
    const int n0 = w * NPW;

    for (int g = 0; g < NPW; g += 4) {
        // scalar startup for 4 chains (3 trans each), then pack into 2 pairs
        float x0s[4], x1s[4], aas[4], nbs[4];
#pragma unroll
        for (int k = 0; k < 4; ++k) {
            const float4 p  = pA[n0 + g + k];   // wave-uniform -> LDS broadcast
            const float4 ww = pW[n0 + g + k];
            // z0 = 2*Cm * exp(dtA * lane)
            float e = __builtin_amdgcn_exp2f(p.x * tf);
            float f = __builtin_amdgcn_fractf(p.y * tf);
            float c = __builtin_amdgcn_cosf(f);
            float s = __builtin_amdgcn_sinf(f);
            float er = e * c, ei = e * s;
            float sr = p.z * er - p.w * ei;     // x0 = Re(z0)
            float si = p.z * ei + p.w * er;
            x0s[k] = sr;
            x1s[k] = sr * ww.x - si * ww.y;     // x1 = Re(z0 * W)
            aas[k] = ww.z;                      // 2*Re(W)
            nbs[k] = ww.w;                      // -|W|^2
        }
        v2f xp0 = (v2f){x0s[0], x0s[1]}, xc0 = (v2f){x1s[0], x1s[1]};
        v2f xp1 = (v2f){x0s[2], x0s[3]}, xc1 = (v2f){x1s[2], x1s[3]};
        const v2f aa0 = (v2f){aas[0], aas[1]}, nb0 = (v2f){nbs[0], nbs[1]};
        const v2f aa1 = (v2f){aas[2], aas[3]}, nb1 = (v2f){nbs[2], nbs[3]};

        acc2[0] += xp0 + xp1;                   // j = 0 contribution
#pragma unroll
        for (int j = 1; j < LPT; ++j) {
            acc2[j] += xc0;                     // v_pk_add_f32
            acc2[j] += xc1;
            v2f t0 = nb0 * xp0;                 // v_pk_mul_f32
            v2f t1 = nb1 * xp1;
            v2f n0v = __builtin_elementwise_fma(aa0, xc0, t0);  // v_pk_fma_f32
            v2f n1v = __builtin_elementwise_fma(aa1, xc1, t1);
            xp0 = xc0; xc0 = n0v;
            xp1 = xc1; xc1 = n1v;
        }
    }

    // stash this wave's 32 partials (horizontal add of the chain pair here);
    // lane stride RJ=33 floats keeps bank aliasing <=2-way (free)
    {
        float* dst = &red[(w * STEP + lane) * RJ];
#pragma unroll
        for (int j = 0; j < LPT; ++j) dst[j] = acc2[j].x + acc2[j].y;
    }
    __syncthreads();

    // sum the 4 wave-partials; 8 outputs per thread, coalesced stores
#pragma unroll
    for (int q = 0; q < 8; ++q) {
        int p  = t + TPB * q;          // 0..2047
        int j  = p >> 6;
        int l2 = p & 63;
        float sum = 0.0f;
#pragma unroll
        for (int v = 0; v < NWAVE; ++v)
            sum += red[(v * STEP + l2) * RJ + j];
        out[h * L + p] = sum;
    }
}

extern "C" void kernel_launch(void* const* d_in, const int* in_sizes, int n_in,
                              void* d_out, int out_size, void* d_ws, size_t ws_size,
                              hipStream_t stream) {
    const float* A_real = (const float*)d_in[0];
    const float* A_imag = (const float*)d_in[1];
    const float* B      = (const float*)d_in[2];
    const float* C      = (const float*)d_in[3];
    const float* inv_dt = (const float*)d_in[4];
    int L = out_size / HH;   // 2048

    s4d_pk_kernel<<<HH, TPB, 0, stream>>>(A_real, A_imag, B, C, inv_dt,
                                          (float*)d_out, L);
}